// Round 8
// baseline (21.335 us; speedup 1.0000x reference)
//
#include <hip/hip_runtime.h>

// MarginRankingLoss over all B*B pairs.
// loss[m,n] = max(0, BIAS - 0.5*(w_m+w_n)*|p_m-p_n|)  (exact per-pair rewrite:
// the gt tie-break only affects r when diff==0, where r*diff==0 anyway).
// Symmetry: loss[m,n]==loss[n,m] (|d| and w-sum commute exactly in IEEE);
// diagonal = BIAS each.  total = 2*sum_{n>m} + B*BIAS.
//
// R8: triangle at the champion geometry (TPB=256, NPT=8, 2048x32 tiles) —
// R2/R3 tested the triangle only with tiny per-thread work / tiny blocks.
// 1D grid of the 640 ACTIVE tiles only (384 clean + 256 diagonal-crossing;
// dead tiles never dispatched). Clean tiles: unmodified R6 packed+med3 loop.
// Crossing tiles: wave-uniform skip of wholly-dead 512-n windows; per-element
// mask only in the single boundary wave.
// Hinge: t1=BIAS-w*d, t2=BIAS+w*d, t1+t2=2*BIAS>0 -> at most one negative ->
// max(0,min(t1,t2)) == v_med3_f32(t1,t2,0) exactly.

#define BIAS_F 0.1f

typedef float v2f __attribute__((ext_vector_type(2)));

constexpr int TPB = 256;       // threads per block
constexpr int NPT = 8;         // n-values per thread
constexpr int NG  = NPT / 2;   // float2 groups
constexpr int TN  = TPB * NPT; // 2048 n per tile
constexpr int TM  = 32;        // m per tile
constexpr int RATIO = TN / TM; // 64

__global__ __launch_bounds__(TPB) void tri_loss_kernel(
    const float* __restrict__ pred,
    const float* __restrict__ weight,
    float* __restrict__ partial,
    int B)
{
    const int tilesM = (B + TM - 1) / TM;
    const int tilesN = (B + TN - 1) / TN;

    // Decode blockIdx.x -> (k = n-tile, mt = m-tile).
    // Segment k holds len_k = min(RATIO*(k+1), tilesM) active m-tiles.
    int bid = blockIdx.x;
    int k = 0, off = 0;
    for (int kk = 0; kk < tilesN; ++kk) {
        int len = min(RATIO * (kk + 1), tilesM);
        if (bid < off + len) { k = kk; break; }
        off += len;
    }
    const int mt = bid - off;
    const int n0 = k * TN;
    const int m0 = mt * TM;
    const int t  = threadIdx.x;
    const int n_first = n0 + 8 * t;   // this thread's first n

    const bool n_in = (n0 + TN <= B);

    // Per-thread n-data: 8 consecutive n -> 4 coalesced float4 loads.
    v2f pn2[NG], wn2[NG];
    if (n_in) {
        const float4* p4 = reinterpret_cast<const float4*>(pred   + n0) + 2 * t;
        const float4* w4 = reinterpret_cast<const float4*>(weight + n0) + 2 * t;
        float4 pa = p4[0], pb = p4[1];
        float4 wa = w4[0], wb = w4[1];
        pn2[0] = (v2f){pa.x, pa.y}; pn2[1] = (v2f){pa.z, pa.w};
        pn2[2] = (v2f){pb.x, pb.y}; pn2[3] = (v2f){pb.z, pb.w};
        wn2[0] = (v2f){wa.x, wa.y} * 0.5f; wn2[1] = (v2f){wa.z, wa.w} * 0.5f;
        wn2[2] = (v2f){wb.x, wb.y} * 0.5f; wn2[3] = (v2f){wb.z, wb.w} * 0.5f;
    } else {
        #pragma unroll
        for (int j = 0; j < NG; ++j) {
            #pragma unroll
            for (int e = 0; e < 2; ++e) {
                int n = n_first + 2 * j + e;
                int nc = (n < B) ? n : 0;
                pn2[j][e] = pred[nc];
                wn2[j][e] = weight[nc] * 0.5f;
            }
        }
    }

    v2f acc2[NG];
    #pragma unroll
    for (int j = 0; j < NG; ++j) acc2[j] = (v2f){0.0f, 0.0f};

    const v2f BIAS2 = (v2f){BIAS_F, BIAS_F};
    const bool clean = n_in && (m0 + TM <= n0);   // every n > every m, all in range

    if (clean) {
        #pragma unroll 4
        for (int i = 0; i < TM; ++i) {
            const int m = m0 + i;
            const float pm  = pred[m];          // uniform -> scalar load
            const float wmh = weight[m] * 0.5f;
            const v2f pm2 = (v2f){pm, pm};
            const v2f wm2 = (v2f){wmh, wmh};
            #pragma unroll
            for (int j = 0; j < NG; ++j) {
                v2f d  = pm2 - pn2[j];                             // v_pk_add
                v2f w  = wm2 + wn2[j];                             // v_pk_add
                v2f t1 = __builtin_elementwise_fma(-w, d, BIAS2);  // v_pk_fma
                v2f t2 = __builtin_elementwise_fma( w, d, BIAS2);  // v_pk_fma
                v2f h;
                h.x = __builtin_amdgcn_fmed3f(t1.x, t2.x, 0.0f);
                h.y = __builtin_amdgcn_fmed3f(t1.y, t2.y, 0.0f);
                acc2[j] += h;                                      // v_pk_add
            }
        }
    } else {
        // Diagonal-crossing (or n-tail) tile. Wave-uniform window skip.
        const int wid  = __builtin_amdgcn_readfirstlane(t >> 6);
        const int wnlo = n0 + wid * 512;          // wave's min n
        const int wnhi = wnlo + 511;              // wave's max n
        const int m_end = (m0 + TM <= B) ? TM : (B - m0);
        for (int i = 0; i < m_end; ++i) {
            const int m = m0 + i;
            if (wnhi <= m) continue;              // no n > m in this wave
            const float pm  = pred[m];
            const float wmh = weight[m] * 0.5f;
            const v2f pm2 = (v2f){pm, pm};
            const v2f wm2 = (v2f){wmh, wmh};
            if (n_in && wnlo > m) {
                // whole wave strictly above diagonal: maskless
                #pragma unroll
                for (int j = 0; j < NG; ++j) {
                    v2f d  = pm2 - pn2[j];
                    v2f w  = wm2 + wn2[j];
                    v2f t1 = __builtin_elementwise_fma(-w, d, BIAS2);
                    v2f t2 = __builtin_elementwise_fma( w, d, BIAS2);
                    v2f h;
                    h.x = __builtin_amdgcn_fmed3f(t1.x, t2.x, 0.0f);
                    h.y = __builtin_amdgcn_fmed3f(t1.y, t2.y, 0.0f);
                    acc2[j] += h;
                }
            } else {
                // boundary wave: per-element mask (n > m, n < B)
                #pragma unroll
                for (int j = 0; j < NG; ++j) {
                    v2f d  = pm2 - pn2[j];
                    v2f w  = wm2 + wn2[j];
                    v2f t1 = __builtin_elementwise_fma(-w, d, BIAS2);
                    v2f t2 = __builtin_elementwise_fma( w, d, BIAS2);
                    float hx = __builtin_amdgcn_fmed3f(t1.x, t2.x, 0.0f);
                    float hy = __builtin_amdgcn_fmed3f(t1.y, t2.y, 0.0f);
                    int nx = n_first + 2 * j, ny = nx + 1;
                    acc2[j].x += (nx > m && nx < B) ? hx : 0.0f;
                    acc2[j].y += (ny > m && ny < B) ? hy : 0.0f;
                }
            }
        }
    }

    float s = 0.0f;
    #pragma unroll
    for (int j = 0; j < NG; ++j) s += acc2[j].x + acc2[j].y;

    // wave (64-lane) reduction
    #pragma unroll
    for (int off2 = 32; off2 > 0; off2 >>= 1)
        s += __shfl_down(s, off2, 64);

    __shared__ float lds[TPB / 64];
    const int lane = t & 63, wid2 = t >> 6;
    if (lane == 0) lds[wid2] = s;
    __syncthreads();
    if (t == 0) {
        float bs = 0.0f;
        #pragma unroll
        for (int w = 0; w < TPB / 64; ++w) bs += lds[w];
        partial[bid] = bs;
    }
}

// One wave, no LDS, no barrier.
__global__ __launch_bounds__(64) void reduce_kernel(
    const float* __restrict__ partial, int n, float* __restrict__ out, int B)
{
    double s = 0.0;
    for (int i = (int)threadIdx.x; i < n; i += 64) s += (double)partial[i];
    #pragma unroll
    for (int off = 32; off > 0; off >>= 1)
        s += __shfl_down(s, off, 64);
    if (threadIdx.x == 0) {
        // full matrix = 2*upper-triangle + B*BIAS (diagonal)
        double full = 2.0 * s + (double)B * (double)BIAS_F;
        out[0] = (float)(full / ((double)B * (double)B));
    }
}

extern "C" void kernel_launch(void* const* d_in, const int* in_sizes, int n_in,
                              void* d_out, int out_size, void* d_ws, size_t ws_size,
                              hipStream_t stream) {
    const float* pred   = (const float*)d_in[0];
    // d_in[1] = correct_output — mathematically irrelevant (see header comment)
    const float* weight = (const float*)d_in[2];
    float* out = (float*)d_out;
    const int B = in_sizes[0];

    const int tilesM = (B + TM - 1) / TM;
    const int tilesN = (B + TN - 1) / TN;
    int nActive = 0;
    for (int k = 0; k < tilesN; ++k) {
        int len = RATIO * (k + 1);
        if (len > tilesM) len = tilesM;
        nActive += len;                    // 640 at B=8192
    }
    float* partial = (float*)d_ws;         // nActive floats

    tri_loss_kernel<<<nActive, TPB, 0, stream>>>(pred, weight, partial, B);
    reduce_kernel<<<1, 64, 0, stream>>>(partial, nActive, out, B);
}